// Round 1
// baseline (943.374 us; speedup 1.0000x reference)
//
#include <hip/hip_runtime.h>
#include <hip/hip_bf16.h>
#include <math.h>

#define T_SEQ 2048
#define BATCH 16
#define C_DIM 64
#define N_H   4
#define HD    16
#define FF    128
#define EPS_LN 1e-5f
#define KT 32

// ---------------------------------------------------------------------------
// Kernel 1: QKV projection.  x[b,t,64] @ Wqkv[192,64]^T -> q,k,v each [b,h,t,16]
// block = 256 threads = 4 tokens (64 lanes/token)
// ---------------------------------------------------------------------------
__global__ __launch_bounds__(256) void qkv_kernel(
    const float* __restrict__ x, const float* __restrict__ Wqkv,
    float* __restrict__ q, float* __restrict__ k, float* __restrict__ v)
{
    int tid  = threadIdx.x;
    int lane = tid & 63;
    int tl   = tid >> 6;
    int token = blockIdx.x * 4 + tl;           // b*T + t
    __shared__ float xs[4][C_DIM];
    xs[tl][lane] = x[token * C_DIM + lane];
    __syncthreads();

    const float* xr = xs[tl];
    float o0 = 0.f, o1 = 0.f, o2 = 0.f;
    const float* w0 = Wqkv + (0 * C_DIM + lane) * C_DIM;
    const float* w1 = Wqkv + (1 * C_DIM + lane) * C_DIM;
    const float* w2 = Wqkv + (2 * C_DIM + lane) * C_DIM;
#pragma unroll
    for (int c = 0; c < C_DIM; c += 4) {
        float4 xv  = *(const float4*)&xr[c];
        float4 wa  = *(const float4*)&w0[c];
        float4 wb  = *(const float4*)&w1[c];
        float4 wc  = *(const float4*)&w2[c];
        o0 += wa.x * xv.x + wa.y * xv.y + wa.z * xv.z + wa.w * xv.w;
        o1 += wb.x * xv.x + wb.y * xv.y + wb.z * xv.z + wb.w * xv.w;
        o2 += wc.x * xv.x + wc.y * xv.y + wc.z * xv.z + wc.w * xv.w;
    }
    int b = token >> 11;            // /T_SEQ
    int t = token & (T_SEQ - 1);
    int h = lane >> 4;
    int d = lane & 15;
    size_t dst = ((size_t)(b * N_H + h) * T_SEQ + t) * HD + d;
    q[dst] = o0;
    k[dst] = o1;
    v[dst] = o2;
}

// ---------------------------------------------------------------------------
// Kernel 2: flash attention (non-causal).  1 thread = 1 query row.
// grid = (B*H) * (T/256) blocks of 256 threads.
// K/V tiles of KT=32 keys staged in LDS; online softmax, per-tile max.
// Output a[b,t,c] with c = h*16+d.
// ---------------------------------------------------------------------------
__global__ __launch_bounds__(256) void attn_kernel(
    const float* __restrict__ q, const float* __restrict__ k,
    const float* __restrict__ v, float* __restrict__ a)
{
    int bh  = blockIdx.x >> 3;          // 0..63
    int qt  = blockIdx.x & 7;
    int tid = threadIdx.x;
    int tq  = qt * 256 + tid;

    const float* qbase = q + ((size_t)bh * T_SEQ + tq) * HD;
    float qr[HD];
#pragma unroll
    for (int i = 0; i < HD; i += 4) {
        float4 t4 = *(const float4*)&qbase[i];
        qr[i] = t4.x; qr[i+1] = t4.y; qr[i+2] = t4.z; qr[i+3] = t4.w;
    }

    __shared__ float Ks[KT][HD];
    __shared__ float Vs[KT][HD];

    float acc[HD];
#pragma unroll
    for (int i = 0; i < HD; i++) acc[i] = 0.f;
    float m = -INFINITY, l = 0.f;

    const float* kb = k + (size_t)bh * T_SEQ * HD;
    const float* vb = v + (size_t)bh * T_SEQ * HD;

    for (int k0 = 0; k0 < T_SEQ; k0 += KT) {
        __syncthreads();
        // stage KT*16 = 512 floats per buffer = 128 float4 each
        if (tid < 128) {
            ((float4*)Ks)[tid]       = ((const float4*)(kb + k0 * HD))[tid];
        } else {
            ((float4*)Vs)[tid - 128] = ((const float4*)(vb + k0 * HD))[tid - 128];
        }
        __syncthreads();

        float s[KT];
        float tmax = -INFINITY;
#pragma unroll
        for (int kk = 0; kk < KT; kk++) {
            float d0 = 0.f;
#pragma unroll
            for (int i = 0; i < HD; i++) d0 += qr[i] * Ks[kk][i];
            s[kk] = d0 * 0.25f;               // scale = hd^-0.5
            tmax = fmaxf(tmax, s[kk]);
        }
        float mnew = fmaxf(m, tmax);
        float corr = __expf(m - mnew);        // exp(-inf)=0 handles first tile
        l *= corr;
#pragma unroll
        for (int i = 0; i < HD; i++) acc[i] *= corr;
#pragma unroll
        for (int kk = 0; kk < KT; kk++) {
            float p = __expf(s[kk] - mnew);
            l += p;
#pragma unroll
            for (int i = 0; i < HD; i++) acc[i] += p * Vs[kk][i];
        }
        m = mnew;
    }

    float inv = 1.0f / l;
    int b = bh >> 2, h = bh & 3;
    float* ab = a + ((size_t)(b * T_SEQ + tq)) * C_DIM + h * HD;
#pragma unroll
    for (int i = 0; i < HD; i += 4) {
        float4 o = make_float4(acc[i]*inv, acc[i+1]*inv, acc[i+2]*inv, acc[i+3]*inv);
        *(float4*)&ab[i] = o;
    }
}

// ---------------------------------------------------------------------------
// Kernel 3: fused tail. proj + residual + LN1 + FFN(relu) + residual + LN2.
// block = 256 threads = 4 tokens (64 lanes/token). wave-shuffle LN reductions.
// ---------------------------------------------------------------------------
__device__ __forceinline__ float wave_sum(float vv) {
#pragma unroll
    for (int o = 32; o > 0; o >>= 1) vv += __shfl_xor(vv, o, 64);
    return vv;
}

__global__ __launch_bounds__(256) void tail_kernel(
    const float* __restrict__ x,  const float* __restrict__ a,
    const float* __restrict__ Wproj,
    const float* __restrict__ W1, const float* __restrict__ b1,
    const float* __restrict__ W2, const float* __restrict__ b2,
    const float* __restrict__ g1, const float* __restrict__ be1,
    const float* __restrict__ g2, const float* __restrict__ be2,
    float* __restrict__ out)
{
    int tid  = threadIdx.x;
    int lane = tid & 63;
    int tl   = tid >> 6;
    int token = blockIdx.x * 4 + tl;

    __shared__ float as_[4][C_DIM];
    __shared__ float x1s[4][C_DIM];
    __shared__ float hs[4][FF];

    as_[tl][lane] = a[token * C_DIM + lane];
    float xd = x[token * C_DIM + lane];
    __syncthreads();

    // proj: y_d = sum_c Wproj[d,c] * a[c]
    float accp = 0.f;
    const float* wr = Wproj + lane * C_DIM;
#pragma unroll
    for (int c = 0; c < C_DIM; c += 4) {
        float4 wv = *(const float4*)&wr[c];
        float4 av = *(const float4*)&as_[tl][c];
        accp += wv.x*av.x + wv.y*av.y + wv.z*av.z + wv.w*av.w;
    }
    float r = xd + accp;

    // LN1
    float mu  = wave_sum(r) * (1.0f / 64.0f);
    float df  = r - mu;
    float var = wave_sum(df * df) * (1.0f / 64.0f);
    float x1  = df * rsqrtf(var + EPS_LN) * g1[lane] + be1[lane];
    x1s[tl][lane] = x1;
    __syncthreads();

    // FFN up: lane computes hidden units f = lane and lane+64
    float h0 = b1[lane], h1 = b1[lane + 64];
    const float* w1a = W1 + lane * C_DIM;
    const float* w1b = W1 + (lane + 64) * C_DIM;
#pragma unroll
    for (int c = 0; c < C_DIM; c += 4) {
        float4 xv = *(const float4*)&x1s[tl][c];
        float4 wa = *(const float4*)&w1a[c];
        float4 wb = *(const float4*)&w1b[c];
        h0 += wa.x*xv.x + wa.y*xv.y + wa.z*xv.z + wa.w*xv.w;
        h1 += wb.x*xv.x + wb.y*xv.y + wb.z*xv.z + wb.w*xv.w;
    }
    hs[tl][lane]      = fmaxf(h0, 0.f);
    hs[tl][lane + 64] = fmaxf(h1, 0.f);
    __syncthreads();

    // FFN down: y_d = b2[d] + sum_f W2[d,f] * h[f]
    float y = b2[lane];
    const float* w2r = W2 + lane * FF;
#pragma unroll
    for (int f = 0; f < FF; f += 4) {
        float4 wv = *(const float4*)&w2r[f];
        float4 hv = *(const float4*)&hs[tl][f];
        y += wv.x*hv.x + wv.y*hv.y + wv.z*hv.z + wv.w*hv.w;
    }
    float r2 = x1 + y;

    // LN2
    float mu2  = wave_sum(r2) * (1.0f / 64.0f);
    float df2  = r2 - mu2;
    float var2 = wave_sum(df2 * df2) * (1.0f / 64.0f);
    float o    = df2 * rsqrtf(var2 + EPS_LN) * g2[lane] + be2[lane];

    out[token * C_DIM + lane] = o;
}

// ---------------------------------------------------------------------------
extern "C" void kernel_launch(void* const* d_in, const int* in_sizes, int n_in,
                              void* d_out, int out_size, void* d_ws, size_t ws_size,
                              hipStream_t stream)
{
    const float* x     = (const float*)d_in[0];
    const float* Wqkv  = (const float*)d_in[1];
    const float* Wproj = (const float*)d_in[2];
    const float* W1    = (const float*)d_in[3];
    const float* b1    = (const float*)d_in[4];
    const float* W2    = (const float*)d_in[5];
    const float* b2    = (const float*)d_in[6];
    const float* g1    = (const float*)d_in[7];
    const float* be1   = (const float*)d_in[8];
    const float* g2    = (const float*)d_in[9];
    const float* be2   = (const float*)d_in[10];
    float* out = (float*)d_out;

    const size_t per = (size_t)BATCH * N_H * T_SEQ * HD;   // 2M floats
    float* q = (float*)d_ws;
    float* k = q + per;
    float* v = k + per;
    float* a = v + per;

    int tokens = BATCH * T_SEQ;                 // 32768
    qkv_kernel<<<tokens / 4, 256, 0, stream>>>(x, Wqkv, q, k, v);

    int attn_blocks = BATCH * N_H * (T_SEQ / 256);   // 512
    attn_kernel<<<attn_blocks, 256, 0, stream>>>(q, k, v, a);

    tail_kernel<<<tokens / 4, 256, 0, stream>>>(x, a, Wproj, W1, b1, W2, b2,
                                                g1, be1, g2, be2, out);
}

// Round 2
// 204.394 us; speedup vs baseline: 4.6155x; 4.6155x over previous
//
#include <hip/hip_runtime.h>
#include <hip/hip_bf16.h>
#include <math.h>

typedef _Float16 h16;
typedef h16   v4h __attribute__((ext_vector_type(4)));
typedef float v4f __attribute__((ext_vector_type(4)));

#define T_SEQ 2048
#define BATCH 16
#define NTOK  (BATCH * T_SEQ)
#define C_DIM 64
#define N_H   4
#define HD    16
#define FF    128
#define EPS_LN 1e-5f

#define MFMA16 __builtin_amdgcn_mfma_f32_16x16x16f16

static __device__ __forceinline__ v4h cvt4(float4 f) {
    v4h r; r[0] = (h16)f.x; r[1] = (h16)f.y; r[2] = (h16)f.z; r[3] = (h16)f.w;
    return r;
}

// ---------------------------------------------------------------------------
// qkv GEMM: x[32768,64] @ Wqkv^T -> q,k f16 [b,h,t,16], vt f16 [b,h,16,t]
// 1 wave = 16 tokens. grid 512 x 256 (4 waves/block).
// ---------------------------------------------------------------------------
__global__ __launch_bounds__(256, 1) void qkv_gemm(
    const float* __restrict__ x, const float* __restrict__ Wqkv,
    h16* __restrict__ q, h16* __restrict__ k, h16* __restrict__ vt)
{
    int tid = threadIdx.x;
    int lane = tid & 63, w = tid >> 6;
    int lm = lane & 15, g4 = (lane >> 4) * 4;
    int tile = blockIdx.x * 4 + w;             // 0..2047
    int t0 = tile * 16;

    // B-frags: B[k=c][n=e] = Wqkv[e][c];  e = n*16+lm, c = kt*16+g4+i
    v4h bf[12][4];
#pragma unroll
    for (int n = 0; n < 12; n++)
#pragma unroll
        for (int kt = 0; kt < 4; kt++)
            bf[n][kt] = cvt4(*(const float4*)(Wqkv + (n*16 + lm)*C_DIM + kt*16 + g4));

    // A-frags: A[m=token][k=c];  token = t0+lm, c = kt*16+g4+i
    v4h af[4];
#pragma unroll
    for (int kt = 0; kt < 4; kt++)
        af[kt] = cvt4(*(const float4*)(x + (size_t)(t0 + lm)*C_DIM + kt*16 + g4));

    int b  = t0 >> 11;              // token/2048
    int tl = t0 & (T_SEQ - 1);
#pragma unroll
    for (int n = 0; n < 12; n++) {
        v4f acc = {0.f, 0.f, 0.f, 0.f};
#pragma unroll
        for (int kt = 0; kt < 4; kt++)
            acc = MFMA16(af[kt], bf[n][kt], acc, 0, 0, 0);
        // D[token = t0+g4+r][e = n*16+lm]
        if (n < 4) {
            h16* qp = q + ((size_t)(b*N_H + n)*T_SEQ + tl + g4)*HD + lm;
#pragma unroll
            for (int r = 0; r < 4; r++) qp[r*HD] = (h16)acc[r];
        } else if (n < 8) {
            h16* kp = k + ((size_t)(b*N_H + (n-4))*T_SEQ + tl + g4)*HD + lm;
#pragma unroll
            for (int r = 0; r < 4; r++) kp[r*HD] = (h16)acc[r];
        } else {
            v4h pk;
#pragma unroll
            for (int r = 0; r < 4; r++) pk[r] = (h16)acc[r];
            *(v4h*)(vt + ((size_t)(b*N_H + (n-8))*HD + lm)*T_SEQ + tl + g4) = pk;
        }
    }
}

// ---------------------------------------------------------------------------
// Flash attention, MFMA 16x16x16, swapped operands.
// 1 wave = 16 query rows of one (b,h). grid 2048 x 256.
//  S^T = mfma(Kfrag, Qfrag): lane holds S^T[key=g4+r][q=lm]
//  acc^T = mfma(Vtfrag, Pfrag, acc): lane holds out^T[d=g4+r][q=lm]
// ---------------------------------------------------------------------------
__global__ __launch_bounds__(256, 1) void attn_mfma(
    const h16* __restrict__ q, const h16* __restrict__ k,
    const h16* __restrict__ vt, h16* __restrict__ a)
{
    int tid = threadIdx.x;
    int lane = tid & 63, w = tid >> 6;
    int lm = lane & 15, g4 = (lane >> 4) * 4;
    int bh = blockIdx.x >> 5;                  // 0..63
    int qt = (blockIdx.x & 31) * 4 + w;        // 0..127

    const float SC = 0.25f * 1.44269504f;      // scale * log2(e)

    v4h qf = *(const v4h*)(q + ((size_t)bh*T_SEQ + qt*16 + lm)*HD + g4);
    const h16* kp = k  + ((size_t)bh*T_SEQ + lm)*HD + g4;
    const h16* vp = vt + ((size_t)bh*HD + lm)*T_SEQ + g4;

    v4f acc = {0.f, 0.f, 0.f, 0.f};
    float mrun = -INFINITY, lrun = 0.f;

    for (int kt = 0; kt < T_SEQ/16; kt++) {
        v4h kf = *(const v4h*)kp;  kp += 256;   // 16 rows * 16
        v4f zero = {0.f, 0.f, 0.f, 0.f};
        v4f st = MFMA16(kf, qf, zero, 0, 0, 0);
        float s0 = st[0]*SC, s1 = st[1]*SC, s2 = st[2]*SC, s3 = st[3]*SC;
        float tm = fmaxf(fmaxf(s0, s1), fmaxf(s2, s3));
        tm = fmaxf(tm, __shfl_xor(tm, 16, 64));
        tm = fmaxf(tm, __shfl_xor(tm, 32, 64));
        float mn = fmaxf(mrun, tm);
        float corr = exp2f(mrun - mn);
        float p0 = exp2f(s0 - mn), p1 = exp2f(s1 - mn);
        float p2 = exp2f(s2 - mn), p3 = exp2f(s3 - mn);
        float ps = (p0 + p1) + (p2 + p3);
        ps += __shfl_xor(ps, 16, 64);
        ps += __shfl_xor(ps, 32, 64);
        lrun = lrun * corr + ps;
        mrun = mn;
        v4h pf; pf[0]=(h16)p0; pf[1]=(h16)p1; pf[2]=(h16)p2; pf[3]=(h16)p3;
        v4h vf = *(const v4h*)(vp + kt*16);
        acc[0]*=corr; acc[1]*=corr; acc[2]*=corr; acc[3]*=corr;
        acc = MFMA16(vf, pf, acc, 0, 0, 0);
    }
    float inv = 1.0f / lrun;
    int b = bh >> 2, h = bh & 3;
    v4h o;
#pragma unroll
    for (int r = 0; r < 4; r++) o[r] = (h16)(acc[r] * inv);
    *(v4h*)(a + ((size_t)(b*T_SEQ) + qt*16 + lm)*C_DIM + h*HD + g4) = o;
}

// ---------------------------------------------------------------------------
// proj GEMM + residual + LN1 -> x1 (fp32 [t,64])
// ---------------------------------------------------------------------------
__global__ __launch_bounds__(256, 1) void proj_ln1(
    const h16* __restrict__ a, const float* __restrict__ x,
    const float* __restrict__ Wproj, const float* __restrict__ g1,
    const float* __restrict__ be1, float* __restrict__ x1)
{
    int tid = threadIdx.x;
    int lane = tid & 63, w = tid >> 6;
    int lm = lane & 15, g4 = (lane >> 4) * 4;
    int tile = blockIdx.x * 4 + w;
    int t0 = tile * 16;

    v4h bf[4][4];
#pragma unroll
    for (int n = 0; n < 4; n++)
#pragma unroll
        for (int kt = 0; kt < 4; kt++)
            bf[n][kt] = cvt4(*(const float4*)(Wproj + (n*16 + lm)*C_DIM + kt*16 + g4));

    v4h af[4];
#pragma unroll
    for (int kt = 0; kt < 4; kt++)
        af[kt] = *(const v4h*)(a + (size_t)(t0 + lm)*C_DIM + kt*16 + g4);

    float rv[4][4];
#pragma unroll
    for (int n = 0; n < 4; n++) {
        v4f acc = {0.f, 0.f, 0.f, 0.f};
#pragma unroll
        for (int kt = 0; kt < 4; kt++)
            acc = MFMA16(af[kt], bf[n][kt], acc, 0, 0, 0);
#pragma unroll
        for (int r = 0; r < 4; r++)
            rv[n][r] = acc[r] + x[(size_t)(t0 + g4 + r)*C_DIM + n*16 + lm];
    }
    float g1v[4], bev[4];
#pragma unroll
    for (int n = 0; n < 4; n++) { g1v[n] = g1[n*16 + lm]; bev[n] = be1[n*16 + lm]; }
#pragma unroll
    for (int r = 0; r < 4; r++) {
        float s = (rv[0][r] + rv[1][r]) + (rv[2][r] + rv[3][r]);
        s += __shfl_xor(s, 1, 64); s += __shfl_xor(s, 2, 64);
        s += __shfl_xor(s, 4, 64); s += __shfl_xor(s, 8, 64);
        float mu = s * (1.f/64.f);
        float d0 = rv[0][r]-mu, d1 = rv[1][r]-mu, d2 = rv[2][r]-mu, d3 = rv[3][r]-mu;
        float qs = d0*d0 + d1*d1 + d2*d2 + d3*d3;
        qs += __shfl_xor(qs, 1, 64); qs += __shfl_xor(qs, 2, 64);
        qs += __shfl_xor(qs, 4, 64); qs += __shfl_xor(qs, 8, 64);
        float is = rsqrtf(qs * (1.f/64.f) + EPS_LN);
        float* xp = x1 + (size_t)(t0 + g4 + r)*C_DIM + lm;
        xp[ 0] = d0*is*g1v[0] + bev[0];
        xp[16] = d1*is*g1v[1] + bev[1];
        xp[32] = d2*is*g1v[2] + bev[2];
        xp[48] = d3*is*g1v[3] + bev[3];
    }
}

// ---------------------------------------------------------------------------
// FFN up GEMM + bias + relu -> hh f16 [t,128]
// ---------------------------------------------------------------------------
__global__ __launch_bounds__(256, 1) void ffn1_gemm(
    const float* __restrict__ x1, const float* __restrict__ W1,
    const float* __restrict__ b1, h16* __restrict__ hh)
{
    int tid = threadIdx.x;
    int lane = tid & 63, w = tid >> 6;
    int lm = lane & 15, g4 = (lane >> 4) * 4;
    int tile = blockIdx.x * 4 + w;
    int t0 = tile * 16;

    v4h bf[8][4];
#pragma unroll
    for (int n = 0; n < 8; n++)
#pragma unroll
        for (int kt = 0; kt < 4; kt++)
            bf[n][kt] = cvt4(*(const float4*)(W1 + (n*16 + lm)*C_DIM + kt*16 + g4));

    v4h af[4];
#pragma unroll
    for (int kt = 0; kt < 4; kt++)
        af[kt] = cvt4(*(const float4*)(x1 + (size_t)(t0 + lm)*C_DIM + kt*16 + g4));

    float b1v[8];
#pragma unroll
    for (int n = 0; n < 8; n++) b1v[n] = b1[n*16 + lm];

#pragma unroll
    for (int n = 0; n < 8; n++) {
        v4f acc = {0.f, 0.f, 0.f, 0.f};
#pragma unroll
        for (int kt = 0; kt < 4; kt++)
            acc = MFMA16(af[kt], bf[n][kt], acc, 0, 0, 0);
        h16* hp = hh + (size_t)(t0 + g4)*FF + n*16 + lm;
#pragma unroll
        for (int r = 0; r < 4; r++)
            hp[r*FF] = (h16)fmaxf(acc[r] + b1v[n], 0.f);
    }
}

// ---------------------------------------------------------------------------
// FFN down GEMM + bias + residual + LN2 -> out fp32
// ---------------------------------------------------------------------------
__global__ __launch_bounds__(256, 1) void ffn2_ln2(
    const h16* __restrict__ hh, const float* __restrict__ x1,
    const float* __restrict__ W2, const float* __restrict__ b2,
    const float* __restrict__ g2, const float* __restrict__ be2,
    float* __restrict__ out)
{
    int tid = threadIdx.x;
    int lane = tid & 63, w = tid >> 6;
    int lm = lane & 15, g4 = (lane >> 4) * 4;
    int tile = blockIdx.x * 4 + w;
    int t0 = tile * 16;

    v4h bf[4][8];
#pragma unroll
    for (int n = 0; n < 4; n++)
#pragma unroll
        for (int kt = 0; kt < 8; kt++)
            bf[n][kt] = cvt4(*(const float4*)(W2 + (n*16 + lm)*FF + kt*16 + g4));

    v4h af[8];
#pragma unroll
    for (int kt = 0; kt < 8; kt++)
        af[kt] = *(const v4h*)(hh + (size_t)(t0 + lm)*FF + kt*16 + g4);

    float b2v[4], g2v[4], bev[4];
#pragma unroll
    for (int n = 0; n < 4; n++) {
        b2v[n] = b2[n*16 + lm]; g2v[n] = g2[n*16 + lm]; bev[n] = be2[n*16 + lm];
    }

    float rv[4][4];
#pragma unroll
    for (int n = 0; n < 4; n++) {
        v4f acc = {0.f, 0.f, 0.f, 0.f};
#pragma unroll
        for (int kt = 0; kt < 8; kt++)
            acc = MFMA16(af[kt], bf[n][kt], acc, 0, 0, 0);
#pragma unroll
        for (int r = 0; r < 4; r++)
            rv[n][r] = acc[r] + b2v[n] + x1[(size_t)(t0 + g4 + r)*C_DIM + n*16 + lm];
    }
#pragma unroll
    for (int r = 0; r < 4; r++) {
        float s = (rv[0][r] + rv[1][r]) + (rv[2][r] + rv[3][r]);
        s += __shfl_xor(s, 1, 64); s += __shfl_xor(s, 2, 64);
        s += __shfl_xor(s, 4, 64); s += __shfl_xor(s, 8, 64);
        float mu = s * (1.f/64.f);
        float d0 = rv[0][r]-mu, d1 = rv[1][r]-mu, d2 = rv[2][r]-mu, d3 = rv[3][r]-mu;
        float qs = d0*d0 + d1*d1 + d2*d2 + d3*d3;
        qs += __shfl_xor(qs, 1, 64); qs += __shfl_xor(qs, 2, 64);
        qs += __shfl_xor(qs, 4, 64); qs += __shfl_xor(qs, 8, 64);
        float is = rsqrtf(qs * (1.f/64.f) + EPS_LN);
        float* op = out + (size_t)(t0 + g4 + r)*C_DIM + lm;
        op[ 0] = d0*is*g2v[0] + bev[0];
        op[16] = d1*is*g2v[1] + bev[1];
        op[32] = d2*is*g2v[2] + bev[2];
        op[48] = d3*is*g2v[3] + bev[3];
    }
}

// ---------------------------------------------------------------------------
extern "C" void kernel_launch(void* const* d_in, const int* in_sizes, int n_in,
                              void* d_out, int out_size, void* d_ws, size_t ws_size,
                              hipStream_t stream)
{
    const float* x     = (const float*)d_in[0];
    const float* Wqkv  = (const float*)d_in[1];
    const float* Wproj = (const float*)d_in[2];
    const float* W1    = (const float*)d_in[3];
    const float* b1    = (const float*)d_in[4];
    const float* W2    = (const float*)d_in[5];
    const float* b2    = (const float*)d_in[6];
    const float* g1    = (const float*)d_in[7];
    const float* be1   = (const float*)d_in[8];
    const float* g2    = (const float*)d_in[9];
    const float* be2   = (const float*)d_in[10];
    float* out = (float*)d_out;

    const size_t perQ = (size_t)BATCH * N_H * T_SEQ * HD;   // 2M elements
    h16* q   = (h16*)d_ws;                       // 4 MB
    h16* kk  = q  + perQ;                        // 4 MB
    h16* vt  = kk + perQ;                        // 4 MB
    h16* a   = vt + perQ;                        // 4 MB  (NTOK*64 f16)
    float* x1 = (float*)(a + (size_t)NTOK * C_DIM);   // 8 MB
    h16* hh  = (h16*)(x1 + (size_t)NTOK * C_DIM);     // 8 MB (NTOK*128 f16)

    qkv_gemm <<<512,  256, 0, stream>>>(x, Wqkv, q, kk, vt);
    attn_mfma<<<2048, 256, 0, stream>>>(q, kk, vt, a);
    proj_ln1 <<<512,  256, 0, stream>>>(a, x, Wproj, g1, be1, x1);
    ffn1_gemm<<<512,  256, 0, stream>>>(x1, W1, b1, hh);
    ffn2_ln2 <<<512,  256, 0, stream>>>(hh, x1, W2, b2, g2, be2, out);
}

// Round 3
// 139.593 us; speedup vs baseline: 6.7580x; 1.4642x over previous
//
#include <hip/hip_runtime.h>
#include <hip/hip_bf16.h>
#include <math.h>

typedef _Float16 h16;
typedef h16   v4h __attribute__((ext_vector_type(4)));
typedef float v4f __attribute__((ext_vector_type(4)));

#define T_SEQ 2048
#define BATCH 16
#define NTOK  (BATCH * T_SEQ)
#define C_DIM 64
#define N_H   4
#define HD    16
#define FF    128
#define EPS_LN 1e-5f
#define MFMA16 __builtin_amdgcn_mfma_f32_16x16x16f16
#define QSCALE (0.25f * 1.44269504089f)   // hd^-0.5 * log2(e)

// ---------------------------------------------------------------------------
// Weight prep: fp32 -> f16 once. 8192 float4 units over 32 blocks.
// ---------------------------------------------------------------------------
__global__ __launch_bounds__(256) void prep_weights(
    const float* __restrict__ Wqkv, const float* __restrict__ Wproj,
    const float* __restrict__ W1,   const float* __restrict__ W2,
    h16* __restrict__ wq, h16* __restrict__ whp,
    h16* __restrict__ wh1, h16* __restrict__ wh2)
{
    int i = blockIdx.x * 256 + threadIdx.x;     // 0..8191
    const float* src; h16* dst; int off;
    if      (i < 3072) { src = Wqkv;  dst = wq;  off = i; }
    else if (i < 4096) { src = Wproj; dst = whp; off = i - 3072; }
    else if (i < 6144) { src = W1;    dst = wh1; off = i - 4096; }
    else               { src = W2;    dst = wh2; off = i - 6144; }
    v4f f = ((const v4f*)src)[off];
    v4h o; o[0]=(h16)f[0]; o[1]=(h16)f[1]; o[2]=(h16)f[2]; o[3]=(h16)f[3];
    ((v4h*)dst)[off] = o;
}

// ---------------------------------------------------------------------------
// qkv GEMM: x[32768,64] @ Wqkv^T -> q (pre-scaled) / k  f16 [b,h,t,16],
// vt f16 [b,h,16,t].  1 wave = 16 tokens.
// ---------------------------------------------------------------------------
__global__ __launch_bounds__(256) void qkv_gemm(
    const float* __restrict__ x, const h16* __restrict__ wq,
    h16* __restrict__ q, h16* __restrict__ k, h16* __restrict__ vt)
{
    int tid = threadIdx.x;
    int lane = tid & 63, w = tid >> 6;
    int lm = lane & 15, g4 = (lane >> 4) * 4;
    int t0 = (blockIdx.x * 4 + w) * 16;

    v4h af[4];
#pragma unroll
    for (int kt = 0; kt < 4; kt++) {
        v4f xv = *(const v4f*)(x + (size_t)(t0 + lm) * C_DIM + kt * 16 + g4);
        v4h c; c[0]=(h16)xv[0]; c[1]=(h16)xv[1]; c[2]=(h16)xv[2]; c[3]=(h16)xv[3];
        af[kt] = c;
    }
    int b = t0 >> 11, tl = t0 & (T_SEQ - 1);
#pragma unroll
    for (int n = 0; n < 12; n++) {
        v4f acc = {0.f, 0.f, 0.f, 0.f};
#pragma unroll
        for (int kt = 0; kt < 4; kt++)
            acc = MFMA16(af[kt], *(const v4h*)(wq + (n*16 + lm)*C_DIM + kt*16 + g4),
                         acc, 0, 0, 0);
        if (n < 4) {
            h16* qp = q + ((size_t)(b*N_H + n)*T_SEQ + tl + g4)*HD + lm;
#pragma unroll
            for (int r = 0; r < 4; r++) qp[r*HD] = (h16)(acc[r] * QSCALE);
        } else if (n < 8) {
            h16* kp = k + ((size_t)(b*N_H + (n-4))*T_SEQ + tl + g4)*HD + lm;
#pragma unroll
            for (int r = 0; r < 4; r++) kp[r*HD] = (h16)acc[r];
        } else {
            v4h pk;
#pragma unroll
            for (int r = 0; r < 4; r++) pk[r] = (h16)acc[r];
            *(v4h*)(vt + ((size_t)(b*N_H + (n-8))*HD + lm)*T_SEQ + tl + g4) = pk;
        }
    }
}

// ---------------------------------------------------------------------------
// Flash attention: 1 wave = 32 queries, tile = 64 keys (4x 16x16x16 MFMA
// per q-group). Defer-max: common path has NO shuffles, NO rescale.
// ---------------------------------------------------------------------------
__global__ __launch_bounds__(256) void attn_mfma(
    const h16* __restrict__ q, const h16* __restrict__ k,
    const h16* __restrict__ vt, h16* __restrict__ a)
{
    int tid = threadIdx.x;
    int lane = tid & 63, w = tid >> 6;
    int lm = lane & 15, g4 = (lane >> 4) * 4;
    int bid = blockIdx.x;
    int W = ((bid & 7) * 128 + (bid >> 3)) * 4 + w;   // XCD swizzle, bijective over 1024*4
    int bh = W >> 6;
    int q0 = (W & 63) * 32;

    v4h qf0 = *(const v4h*)(q + ((size_t)bh*T_SEQ + q0      + lm)*HD + g4);
    v4h qf1 = *(const v4h*)(q + ((size_t)bh*T_SEQ + q0 + 16 + lm)*HD + g4);
    const h16* kp = k  + ((size_t)bh*T_SEQ + lm)*HD + g4;
    const h16* vp = vt + ((size_t)bh*HD + lm)*T_SEQ + g4;

    v4f accA0={0,0,0,0}, accB0={0,0,0,0}, accA1={0,0,0,0}, accB1={0,0,0,0};
    float m0 = -INFINITY, m1 = -INFINITY, l0 = 0.f, l1 = 0.f;

    for (int k0 = 0; k0 < T_SEQ; k0 += 64) {
        v4h kf[4], vf[4];
#pragma unroll
        for (int m = 0; m < 4; m++) {
            kf[m] = *(const v4h*)(kp + (size_t)(k0 + 16*m)*HD);
            vf[m] = *(const v4h*)(vp + k0 + 16*m);
        }
        v4f z = {0.f, 0.f, 0.f, 0.f};
        v4f s0[4], s1[4];
#pragma unroll
        for (int m = 0; m < 4; m++) {
            s0[m] = MFMA16(kf[m], qf0, z, 0, 0, 0);
            s1[m] = MFMA16(kf[m], qf1, z, 0, 0, 0);
        }
        float mx0 = s0[0][0], mx1 = s1[0][0];
#pragma unroll
        for (int m = 0; m < 4; m++) {
#pragma unroll
            for (int i = 0; i < 4; i++) {
                mx0 = fmaxf(mx0, s0[m][i]);
                mx1 = fmaxf(mx1, s1[m][i]);
            }
        }
        if (!__all((mx0 <= m0 + 8.f) && (mx1 <= m1 + 8.f))) {
            float M0 = fmaxf(mx0, __shfl_xor(mx0, 16, 64)); M0 = fmaxf(M0, __shfl_xor(M0, 32, 64));
            float M1 = fmaxf(mx1, __shfl_xor(mx1, 16, 64)); M1 = fmaxf(M1, __shfl_xor(M1, 32, 64));
            float n0 = fmaxf(m0, M0), n1 = fmaxf(m1, M1);
            float c0 = exp2f(m0 - n0), c1 = exp2f(m1 - n1);
            l0 *= c0; l1 *= c1;
#pragma unroll
            for (int i = 0; i < 4; i++) {
                accA0[i]*=c0; accB0[i]*=c0; accA1[i]*=c1; accB1[i]*=c1;
            }
            m0 = n0; m1 = n1;
        }
#pragma unroll
        for (int m = 0; m < 4; m++) {
            v4h p0, p1;
#pragma unroll
            for (int i = 0; i < 4; i++) {
                float e0 = exp2f(s0[m][i] - m0);
                float e1 = exp2f(s1[m][i] - m1);
                l0 += e0; l1 += e1;
                p0[i] = (h16)e0; p1[i] = (h16)e1;
            }
            if (m & 1) { accB0 = MFMA16(vf[m], p0, accB0, 0,0,0); accB1 = MFMA16(vf[m], p1, accB1, 0,0,0); }
            else       { accA0 = MFMA16(vf[m], p0, accA0, 0,0,0); accA1 = MFMA16(vf[m], p1, accA1, 0,0,0); }
        }
    }
    l0 += __shfl_xor(l0, 16, 64); l0 += __shfl_xor(l0, 32, 64);
    l1 += __shfl_xor(l1, 16, 64); l1 += __shfl_xor(l1, 32, 64);
    float i0 = 1.f / l0, i1 = 1.f / l1;
    int b = bh >> 2, h = bh & 3;
    v4h o0, o1;
#pragma unroll
    for (int r = 0; r < 4; r++) {
        o0[r] = (h16)((accA0[r] + accB0[r]) * i0);
        o1[r] = (h16)((accA1[r] + accB1[r]) * i1);
    }
    *(v4h*)(a + ((size_t)(b*T_SEQ) + q0      + lm)*C_DIM + h*HD + g4) = o0;
    *(v4h*)(a + ((size_t)(b*T_SEQ) + q0 + 16 + lm)*C_DIM + h*HD + g4) = o1;
}

// ---------------------------------------------------------------------------
// Fused tail: proj + residual + LN1 + FFN1 + ReLU + FFN2 + residual + LN2.
// Transposed orientation (A=weight, B=activation^T): each stage's output
// fragment IS the next stage's B fragment -> zero LDS, zero HBM intermediates.
// 1 wave = 16 tokens.
// ---------------------------------------------------------------------------
__global__ __launch_bounds__(256) void tail_fused(
    const h16* __restrict__ a, const float* __restrict__ x,
    const h16* __restrict__ whp, const h16* __restrict__ wh1, const h16* __restrict__ wh2,
    const float* __restrict__ b1, const float* __restrict__ b2,
    const float* __restrict__ g1, const float* __restrict__ be1,
    const float* __restrict__ g2, const float* __restrict__ be2,
    float* __restrict__ out)
{
    int tid = threadIdx.x;
    int lane = tid & 63, w = tid >> 6;
    int lm = lane & 15, g4 = (lane >> 4) * 4;
    int t0 = (blockIdx.x * 4 + w) * 16;

    v4h af[4];
#pragma unroll
    for (int kt = 0; kt < 4; kt++)
        af[kt] = *(const v4h*)(a + (size_t)(t0 + lm)*C_DIM + kt*16 + g4);

    // ---- proj + residual + LN1 ----
    float rvn[4][4];        // x1 (post-LN1), [cn][r]: channel cn*16+g4+r, token t0+lm
    v4h x1t[4];
    {
        v4f rv[4];
#pragma unroll
        for (int cn = 0; cn < 4; cn++) {
            v4f acc = {0.f, 0.f, 0.f, 0.f};
#pragma unroll
            for (int kt = 0; kt < 4; kt++)
                acc = MFMA16(*(const v4h*)(whp + (cn*16 + lm)*C_DIM + kt*16 + g4),
                             af[kt], acc, 0, 0, 0);
            v4f xr = *(const v4f*)(x + (size_t)(t0 + lm)*C_DIM + cn*16 + g4);
            rv[cn] = acc + xr;
        }
        float s = 0.f;
#pragma unroll
        for (int cn = 0; cn < 4; cn++)
#pragma unroll
            for (int i = 0; i < 4; i++) s += rv[cn][i];
        s += __shfl_xor(s, 16, 64); s += __shfl_xor(s, 32, 64);
        float mu = s * (1.f/64.f);
        float qs = 0.f;
#pragma unroll
        for (int cn = 0; cn < 4; cn++)
#pragma unroll
            for (int i = 0; i < 4; i++) { float d = rv[cn][i] - mu; qs += d*d; }
        qs += __shfl_xor(qs, 16, 64); qs += __shfl_xor(qs, 32, 64);
        float is = rsqrtf(qs * (1.f/64.f) + EPS_LN);
#pragma unroll
        for (int cn = 0; cn < 4; cn++) {
            v4f g1v = *(const v4f*)(g1 + cn*16 + g4);
            v4f bev = *(const v4f*)(be1 + cn*16 + g4);
#pragma unroll
            for (int i = 0; i < 4; i++) {
                float vl = (rv[cn][i] - mu) * is * g1v[i] + bev[i];
                rvn[cn][i] = vl;
                x1t[cn][i] = (h16)vl;
            }
        }
    }
    __builtin_amdgcn_sched_barrier(0);

    // ---- FFN1 + ReLU ----
    v4h ht[8];
#pragma unroll
    for (int nf = 0; nf < 8; nf++) {
        v4f acc = {0.f, 0.f, 0.f, 0.f};
#pragma unroll
        for (int kt = 0; kt < 4; kt++)
            acc = MFMA16(*(const v4h*)(wh1 + (nf*16 + lm)*C_DIM + kt*16 + g4),
                         x1t[kt], acc, 0, 0, 0);
        v4f b1v = *(const v4f*)(b1 + nf*16 + g4);
#pragma unroll
        for (int i = 0; i < 4; i++) ht[nf][i] = (h16)fmaxf(acc[i] + b1v[i], 0.f);
    }
    __builtin_amdgcn_sched_barrier(0);

    // ---- FFN2 + residual + LN2 ----
    float yv[4][4];
#pragma unroll
    for (int cn = 0; cn < 4; cn++) {
        v4f acc = {0.f, 0.f, 0.f, 0.f};
#pragma unroll
        for (int kf2 = 0; kf2 < 8; kf2++)
            acc = MFMA16(*(const v4h*)(wh2 + (cn*16 + lm)*FF + kf2*16 + g4),
                         ht[kf2], acc, 0, 0, 0);
        v4f b2v = *(const v4f*)(b2 + cn*16 + g4);
#pragma unroll
        for (int i = 0; i < 4; i++) yv[cn][i] = acc[i] + b2v[i] + rvn[cn][i];
    }
    float s2 = 0.f;
#pragma unroll
    for (int cn = 0; cn < 4; cn++)
#pragma unroll
        for (int i = 0; i < 4; i++) s2 += yv[cn][i];
    s2 += __shfl_xor(s2, 16, 64); s2 += __shfl_xor(s2, 32, 64);
    float mu2 = s2 * (1.f/64.f);
    float qs2 = 0.f;
#pragma unroll
    for (int cn = 0; cn < 4; cn++)
#pragma unroll
        for (int i = 0; i < 4; i++) { float d = yv[cn][i] - mu2; qs2 += d*d; }
    qs2 += __shfl_xor(qs2, 16, 64); qs2 += __shfl_xor(qs2, 32, 64);
    float is2 = rsqrtf(qs2 * (1.f/64.f) + EPS_LN);
#pragma unroll
    for (int cn = 0; cn < 4; cn++) {
        v4f g2v = *(const v4f*)(g2 + cn*16 + g4);
        v4f bev = *(const v4f*)(be2 + cn*16 + g4);
        v4f o;
#pragma unroll
        for (int i = 0; i < 4; i++) o[i] = (yv[cn][i] - mu2) * is2 * g2v[i] + bev[i];
        *(v4f*)(out + (size_t)(t0 + lm)*C_DIM + cn*16 + g4) = o;
    }
}

// ---------------------------------------------------------------------------
extern "C" void kernel_launch(void* const* d_in, const int* in_sizes, int n_in,
                              void* d_out, int out_size, void* d_ws, size_t ws_size,
                              hipStream_t stream)
{
    const float* x     = (const float*)d_in[0];
    const float* Wqkv  = (const float*)d_in[1];
    const float* Wproj = (const float*)d_in[2];
    const float* W1    = (const float*)d_in[3];
    const float* b1    = (const float*)d_in[4];
    const float* W2    = (const float*)d_in[5];
    const float* b2    = (const float*)d_in[6];
    const float* g1    = (const float*)d_in[7];
    const float* be1   = (const float*)d_in[8];
    const float* g2    = (const float*)d_in[9];
    const float* be2   = (const float*)d_in[10];
    float* out = (float*)d_out;

    const size_t perQ = (size_t)BATCH * N_H * T_SEQ * HD;   // 2M elements
    h16* q   = (h16*)d_ws;
    h16* kk  = q  + perQ;
    h16* vt  = kk + perQ;
    h16* a   = vt + perQ;
    h16* wq  = a  + (size_t)NTOK * C_DIM;
    h16* whp = wq  + 3 * C_DIM * C_DIM;     // 12288
    h16* wh1 = whp + C_DIM * C_DIM;         // 4096
    h16* wh2 = wh1 + FF * C_DIM;            // 8192

    prep_weights<<<32,  256, 0, stream>>>(Wqkv, Wproj, W1, W2, wq, whp, wh1, wh2);
    qkv_gemm   <<<512,  256, 0, stream>>>(x, wq, q, kk, vt);
    attn_mfma  <<<1024, 256, 0, stream>>>(q, kk, vt, a);
    tail_fused <<<512,  256, 0, stream>>>(a, x, whp, wh1, wh2, b1, b2,
                                          g1, be1, g2, be2, out);
}

// Round 5
// 127.653 us; speedup vs baseline: 7.3901x; 1.0935x over previous
//
#include <hip/hip_runtime.h>
#include <hip/hip_bf16.h>
#include <math.h>

typedef _Float16 h16;
typedef h16   v4h __attribute__((ext_vector_type(4)));
typedef h16   h2  __attribute__((ext_vector_type(2)));
typedef float v4f __attribute__((ext_vector_type(4)));

#define T_SEQ 2048
#define BATCH 16
#define NTOK  (BATCH * T_SEQ)
#define C_DIM 64
#define N_H   4
#define HD    16
#define FF    128
#define EPS_LN 1e-5f
#define MFMA16 __builtin_amdgcn_mfma_f32_16x16x16f16
#define QSCALE (0.25f * 1.44269504089f)   // hd^-0.5 * log2(e)

static __device__ __forceinline__ float fexp2(float x) {
#if __has_builtin(__builtin_amdgcn_exp2f)
    return __builtin_amdgcn_exp2f(x);
#else
    float r; asm volatile("v_exp_f32 %0, %1" : "=v"(r) : "v"(x)); return r;
#endif
}
static __device__ __forceinline__ float frcp(float x) {
#if __has_builtin(__builtin_amdgcn_rcpf)
    return __builtin_amdgcn_rcpf(x);
#else
    return 1.0f / x;
#endif
}
static __device__ __forceinline__ float frsq(float x) {
#if __has_builtin(__builtin_amdgcn_rsqf)
    return __builtin_amdgcn_rsqf(x);
#else
    return rsqrtf(x);
#endif
}
static __device__ __forceinline__ h2 pk2(float lo, float hi) {
    return __builtin_bit_cast(h2, __builtin_amdgcn_cvt_pkrtz(lo, hi));
}
static __device__ __forceinline__ float fdot2p(h2 a, float acc) {
#if __has_builtin(__builtin_amdgcn_fdot2)
    const h2 one2 = {(h16)1.0f, (h16)1.0f};
    return __builtin_amdgcn_fdot2(a, one2, acc, false);
#else
    return acc + (float)a[0] + (float)a[1];
#endif
}
static __device__ __forceinline__ float m4(v4f v) {
    return fmaxf(fmaxf(v[0], v[1]), fmaxf(v[2], v[3]));
}

// ---------------------------------------------------------------------------
// Weight prep: fp32 -> f16 once.
// ---------------------------------------------------------------------------
__global__ __launch_bounds__(256) void prep_weights(
    const float* __restrict__ Wqkv, const float* __restrict__ Wproj,
    const float* __restrict__ W1,   const float* __restrict__ W2,
    h16* __restrict__ wq, h16* __restrict__ whp,
    h16* __restrict__ wh1, h16* __restrict__ wh2)
{
    int i = blockIdx.x * 256 + threadIdx.x;     // 0..8191
    const float* src; h16* dst; int off;
    if      (i < 3072) { src = Wqkv;  dst = wq;  off = i; }
    else if (i < 4096) { src = Wproj; dst = whp; off = i - 3072; }
    else if (i < 6144) { src = W1;    dst = wh1; off = i - 4096; }
    else               { src = W2;    dst = wh2; off = i - 6144; }
    v4f f = ((const v4f*)src)[off];
    v4h o; o[0]=(h16)f[0]; o[1]=(h16)f[1]; o[2]=(h16)f[2]; o[3]=(h16)f[3];
    ((v4h*)dst)[off] = o;
}

// ---------------------------------------------------------------------------
// qkv GEMM: x[32768,64] @ Wqkv^T -> q (pre-scaled) / k  f16 [b,h,t,16],
// vt f16 [b,h,16,t].  1 wave = 16 tokens.
// ---------------------------------------------------------------------------
__global__ __launch_bounds__(256) void qkv_gemm(
    const float* __restrict__ x, const h16* __restrict__ wq,
    h16* __restrict__ q, h16* __restrict__ k, h16* __restrict__ vt)
{
    int tid = threadIdx.x;
    int lane = tid & 63, w = tid >> 6;
    int lm = lane & 15, g4 = (lane >> 4) * 4;
    int t0 = (blockIdx.x * 4 + w) * 16;

    v4h af[4];
#pragma unroll
    for (int kt = 0; kt < 4; kt++) {
        v4f xv = *(const v4f*)(x + (size_t)(t0 + lm) * C_DIM + kt * 16 + g4);
        v4h c; c[0]=(h16)xv[0]; c[1]=(h16)xv[1]; c[2]=(h16)xv[2]; c[3]=(h16)xv[3];
        af[kt] = c;
    }
    int b = t0 >> 11, tl = t0 & (T_SEQ - 1);
#pragma unroll
    for (int n = 0; n < 12; n++) {
        v4f acc = {0.f, 0.f, 0.f, 0.f};
#pragma unroll
        for (int kt = 0; kt < 4; kt++)
            acc = MFMA16(af[kt], *(const v4h*)(wq + (n*16 + lm)*C_DIM + kt*16 + g4),
                         acc, 0, 0, 0);
        if (n < 4) {
            h16* qp = q + ((size_t)(b*N_H + n)*T_SEQ + tl + g4)*HD + lm;
#pragma unroll
            for (int r = 0; r < 4; r++) qp[r*HD] = (h16)(acc[r] * QSCALE);
        } else if (n < 8) {
            h16* kp = k + ((size_t)(b*N_H + (n-4))*T_SEQ + tl + g4)*HD + lm;
#pragma unroll
            for (int r = 0; r < 4; r++) kp[r*HD] = (h16)acc[r];
        } else {
            v4h pk;
#pragma unroll
            for (int r = 0; r < 4; r++) pk[r] = (h16)acc[r];
            *(v4h*)(vt + ((size_t)(b*N_H + (n-8))*HD + lm)*T_SEQ + tl + g4) = pk;
        }
    }
}

// ---------------------------------------------------------------------------
// Flash attention: 1 wave = 32 queries, tile = 64 keys.
// Packed-f16 softmax: raw v_exp_f32, cvt_pkrtz pack, fdot2 row-sum.
// Defer-max: common path has NO shuffles, NO rescale.
// ---------------------------------------------------------------------------
__global__ __launch_bounds__(256) void attn_mfma(
    const h16* __restrict__ q, const h16* __restrict__ k,
    const h16* __restrict__ vt, h16* __restrict__ a)
{
    int tid = threadIdx.x;
    int lane = tid & 63, w = tid >> 6;
    int lm = lane & 15, g4 = (lane >> 4) * 4;
    int bid = blockIdx.x;
    int W = ((bid & 7) * 128 + (bid >> 3)) * 4 + w;   // XCD swizzle, bijective
    int bh = W >> 6;
    int q0 = (W & 63) * 32;

    v4h qf0 = *(const v4h*)(q + ((size_t)bh*T_SEQ + q0      + lm)*HD + g4);
    v4h qf1 = *(const v4h*)(q + ((size_t)bh*T_SEQ + q0 + 16 + lm)*HD + g4);
    const h16* kp = k  + ((size_t)bh*T_SEQ + lm)*HD + g4;
    const h16* vp = vt + ((size_t)bh*HD + lm)*T_SEQ + g4;

    v4f accA0={0,0,0,0}, accB0={0,0,0,0}, accA1={0,0,0,0}, accB1={0,0,0,0};
    float m0 = -INFINITY, m1 = -INFINITY;
    float l0a = 0.f, l0b = 0.f, l1a = 0.f, l1b = 0.f;

    for (int k0 = 0; k0 < T_SEQ; k0 += 64) {
        v4h kf[4], vf[4];
#pragma unroll
        for (int m = 0; m < 4; m++) {
            kf[m] = *(const v4h*)(kp + (size_t)(k0 + 16*m)*HD);
            vf[m] = *(const v4h*)(vp + k0 + 16*m);
        }
        v4f z = {0.f, 0.f, 0.f, 0.f};
        v4f s0[4], s1[4];
#pragma unroll
        for (int m = 0; m < 4; m++) {
            s0[m] = MFMA16(kf[m], qf0, z, 0, 0, 0);
            s1[m] = MFMA16(kf[m], qf1, z, 0, 0, 0);
        }
        // max-reduce as ternary trees (v_max3-friendly)
        float mx0 = fmaxf(fmaxf(m4(s0[0]), m4(s0[1])), fmaxf(m4(s0[2]), m4(s0[3])));
        float mx1 = fmaxf(fmaxf(m4(s1[0]), m4(s1[1])), fmaxf(m4(s1[2]), m4(s1[3])));

        if (!__all((mx0 <= m0 + 8.f) && (mx1 <= m1 + 8.f))) {
            float M0 = fmaxf(mx0, __shfl_xor(mx0, 16, 64)); M0 = fmaxf(M0, __shfl_xor(M0, 32, 64));
            float M1 = fmaxf(mx1, __shfl_xor(mx1, 16, 64)); M1 = fmaxf(M1, __shfl_xor(M1, 32, 64));
            float n0 = fmaxf(m0, M0), n1 = fmaxf(m1, M1);
            float c0 = fexp2(m0 - n0), c1 = fexp2(m1 - n1);
            l0a *= c0; l0b *= c0; l1a *= c1; l1b *= c1;
#pragma unroll
            for (int i = 0; i < 4; i++) {
                accA0[i]*=c0; accB0[i]*=c0; accA1[i]*=c1; accB1[i]*=c1;
            }
            m0 = n0; m1 = n1;
        }
#pragma unroll
        for (int m = 0; m < 4; m++) {
            v4f s0m = s0[m], s1m = s1[m];
            h2 a0 = pk2(fexp2(s0m[0]-m0), fexp2(s0m[1]-m0));
            h2 b0 = pk2(fexp2(s0m[2]-m0), fexp2(s0m[3]-m0));
            h2 a1 = pk2(fexp2(s1m[0]-m1), fexp2(s1m[1]-m1));
            h2 b1 = pk2(fexp2(s1m[2]-m1), fexp2(s1m[3]-m1));
            l0a = fdot2p(a0, l0a); l0b = fdot2p(b0, l0b);
            l1a = fdot2p(a1, l1a); l1b = fdot2p(b1, l1b);
            v4h p0 = __builtin_shufflevector(a0, b0, 0, 1, 2, 3);
            v4h p1 = __builtin_shufflevector(a1, b1, 0, 1, 2, 3);
            if (m & 1) { accB0 = MFMA16(vf[m], p0, accB0, 0,0,0); accB1 = MFMA16(vf[m], p1, accB1, 0,0,0); }
            else       { accA0 = MFMA16(vf[m], p0, accA0, 0,0,0); accA1 = MFMA16(vf[m], p1, accA1, 0,0,0); }
        }
    }
    float l0 = l0a + l0b, l1 = l1a + l1b;
    l0 += __shfl_xor(l0, 16, 64); l0 += __shfl_xor(l0, 32, 64);
    l1 += __shfl_xor(l1, 16, 64); l1 += __shfl_xor(l1, 32, 64);
    float i0 = frcp(l0), i1 = frcp(l1);
    int b = bh >> 2, h = bh & 3;
    v4h o0, o1;
#pragma unroll
    for (int r = 0; r < 4; r++) {
        o0[r] = (h16)((accA0[r] + accB0[r]) * i0);
        o1[r] = (h16)((accA1[r] + accB1[r]) * i1);
    }
    *(v4h*)(a + ((size_t)(b*T_SEQ) + q0      + lm)*C_DIM + h*HD + g4) = o0;
    *(v4h*)(a + ((size_t)(b*T_SEQ) + q0 + 16 + lm)*C_DIM + h*HD + g4) = o1;
}

// ---------------------------------------------------------------------------
// Fused tail: proj + residual + LN1 + FFN1 + ReLU + FFN2 + residual + LN2.
// ---------------------------------------------------------------------------
__global__ __launch_bounds__(256) void tail_fused(
    const h16* __restrict__ a, const float* __restrict__ x,
    const h16* __restrict__ whp, const h16* __restrict__ wh1, const h16* __restrict__ wh2,
    const float* __restrict__ b1, const float* __restrict__ b2,
    const float* __restrict__ g1, const float* __restrict__ be1,
    const float* __restrict__ g2, const float* __restrict__ be2,
    float* __restrict__ out)
{
    int tid = threadIdx.x;
    int lane = tid & 63, w = tid >> 6;
    int lm = lane & 15, g4 = (lane >> 4) * 4;
    int t0 = (blockIdx.x * 4 + w) * 16;

    v4h af[4];
#pragma unroll
    for (int kt = 0; kt < 4; kt++)
        af[kt] = *(const v4h*)(a + (size_t)(t0 + lm)*C_DIM + kt*16 + g4);

    // ---- proj + residual + LN1 ----
    float rvn[4][4];
    v4h x1t[4];
    {
        v4f rv[4];
#pragma unroll
        for (int cn = 0; cn < 4; cn++) {
            v4f acc = {0.f, 0.f, 0.f, 0.f};
#pragma unroll
            for (int kt = 0; kt < 4; kt++)
                acc = MFMA16(*(const v4h*)(whp + (cn*16 + lm)*C_DIM + kt*16 + g4),
                             af[kt], acc, 0, 0, 0);
            v4f xr = *(const v4f*)(x + (size_t)(t0 + lm)*C_DIM + cn*16 + g4);
            rv[cn] = acc + xr;
        }
        float s = 0.f;
#pragma unroll
        for (int cn = 0; cn < 4; cn++)
#pragma unroll
            for (int i = 0; i < 4; i++) s += rv[cn][i];
        s += __shfl_xor(s, 16, 64); s += __shfl_xor(s, 32, 64);
        float mu = s * (1.f/64.f);
        float qs = 0.f;
#pragma unroll
        for (int cn = 0; cn < 4; cn++)
#pragma unroll
            for (int i = 0; i < 4; i++) { float d = rv[cn][i] - mu; qs += d*d; }
        qs += __shfl_xor(qs, 16, 64); qs += __shfl_xor(qs, 32, 64);
        float is = frsq(qs * (1.f/64.f) + EPS_LN);
#pragma unroll
        for (int cn = 0; cn < 4; cn++) {
            v4f g1v = *(const v4f*)(g1 + cn*16 + g4);
            v4f bev = *(const v4f*)(be1 + cn*16 + g4);
#pragma unroll
            for (int i = 0; i < 4; i++) {
                float vl = (rv[cn][i] - mu) * is * g1v[i] + bev[i];
                rvn[cn][i] = vl;
                x1t[cn][i] = (h16)vl;
            }
        }
    }
    __builtin_amdgcn_sched_barrier(0);

    // ---- FFN1 + ReLU ----
    v4h ht[8];
#pragma unroll
    for (int nf = 0; nf < 8; nf++) {
        v4f acc = {0.f, 0.f, 0.f, 0.f};
#pragma unroll
        for (int kt = 0; kt < 4; kt++)
            acc = MFMA16(*(const v4h*)(wh1 + (nf*16 + lm)*C_DIM + kt*16 + g4),
                         x1t[kt], acc, 0, 0, 0);
        v4f b1v = *(const v4f*)(b1 + nf*16 + g4);
#pragma unroll
        for (int i = 0; i < 4; i++) ht[nf][i] = (h16)fmaxf(acc[i] + b1v[i], 0.f);
    }
    __builtin_amdgcn_sched_barrier(0);

    // ---- FFN2 + residual + LN2 ----
    float yv[4][4];
#pragma unroll
    for (int cn = 0; cn < 4; cn++) {
        v4f acc = {0.f, 0.f, 0.f, 0.f};
#pragma unroll
        for (int kf2 = 0; kf2 < 8; kf2++)
            acc = MFMA16(*(const v4h*)(wh2 + (cn*16 + lm)*FF + kf2*16 + g4),
                         ht[kf2], acc, 0, 0, 0);
        v4f b2v = *(const v4f*)(b2 + cn*16 + g4);
#pragma unroll
        for (int i = 0; i < 4; i++) yv[cn][i] = acc[i] + b2v[i] + rvn[cn][i];
    }
    float s2 = 0.f;
#pragma unroll
    for (int cn = 0; cn < 4; cn++)
#pragma unroll
        for (int i = 0; i < 4; i++) s2 += yv[cn][i];
    s2 += __shfl_xor(s2, 16, 64); s2 += __shfl_xor(s2, 32, 64);
    float mu2 = s2 * (1.f/64.f);
    float qs2 = 0.f;
#pragma unroll
    for (int cn = 0; cn < 4; cn++)
#pragma unroll
        for (int i = 0; i < 4; i++) { float d = yv[cn][i] - mu2; qs2 += d*d; }
    qs2 += __shfl_xor(qs2, 16, 64); qs2 += __shfl_xor(qs2, 32, 64);
    float is2 = frsq(qs2 * (1.f/64.f) + EPS_LN);
#pragma unroll
    for (int cn = 0; cn < 4; cn++) {
        v4f g2v = *(const v4f*)(g2 + cn*16 + g4);
        v4f bev = *(const v4f*)(be2 + cn*16 + g4);
        v4f o;
#pragma unroll
        for (int i = 0; i < 4; i++) o[i] = (yv[cn][i] - mu2) * is2 * g2v[i] + bev[i];
        *(v4f*)(out + (size_t)(t0 + lm)*C_DIM + cn*16 + g4) = o;
    }
}

// ---------------------------------------------------------------------------
extern "C" void kernel_launch(void* const* d_in, const int* in_sizes, int n_in,
                              void* d_out, int out_size, void* d_ws, size_t ws_size,
                              hipStream_t stream)
{
    const float* x     = (const float*)d_in[0];
    const float* Wqkv  = (const float*)d_in[1];
    const float* Wproj = (const float*)d_in[2];
    const float* W1    = (const float*)d_in[3];
    const float* b1    = (const float*)d_in[4];
    const float* W2    = (const float*)d_in[5];
    const float* b2    = (const float*)d_in[6];
    const float* g1    = (const float*)d_in[7];
    const float* be1   = (const float*)d_in[8];
    const float* g2    = (const float*)d_in[9];
    const float* be2   = (const float*)d_in[10];
    float* out = (float*)d_out;

    const size_t perQ = (size_t)BATCH * N_H * T_SEQ * HD;   // 2M elements
    h16* q   = (h16*)d_ws;
    h16* kk  = q  + perQ;
    h16* vt  = kk + perQ;
    h16* a   = vt + perQ;
    h16* wq  = a  + (size_t)NTOK * C_DIM;
    h16* whp = wq  + 3 * C_DIM * C_DIM;
    h16* wh1 = whp + C_DIM * C_DIM;
    h16* wh2 = wh1 + FF * C_DIM;

    prep_weights<<<32,  256, 0, stream>>>(Wqkv, Wproj, W1, W2, wq, whp, wh1, wh2);
    qkv_gemm   <<<512,  256, 0, stream>>>(x, wq, q, kk, vt);
    attn_mfma  <<<1024, 256, 0, stream>>>(q, kk, vt, a);
    tail_fused <<<512,  256, 0, stream>>>(a, x, whp, wh1, wh2, b1, b2,
                                          g1, be1, g2, be2, out);
}